// Round 22
// baseline (209.339 us; speedup 1.0000x reference)
//
#include <hip/hip_runtime.h>

// MADE / PixelCNN autoregressive inverse (all fp32, per reference).
//
// FINAL STRUCTURE (r11/r18/r19/r21, session best: 125.2us rocprof /
// 207.4us harness). On-chain shaves win ~1:1 (divide removal -5.7us,
// compact butterfly -5.8us); off-chain changes are hidden or regress.
// r20: DOTU in helpers regressed (LDS pipe saturation) -> helpers DOT16.
// r22: h0's W-tap from REGISTERS (y0..y3, which every lane already
// computes in the epi) instead of re-reading the yb float4 lane 0 just
// wrote -> removes a write->lgkmcnt->read LDS round-trip (~50-120cy) from
// the per-pixel chain. j==0 guard reproduces the pad zero; values are the
// identical floats -> bit-identical to r21. N-tap reads (old rows) hoisted
// before the epi so their LDS latency overlaps the expf chain.
//
// Design-space sweep (22 rounds): sync {6-bar, 2-bar, spin-flags x3},
// split {16/12/8/4/2 waves}, MAC {readlane, LDS-broadcast, reg}, slots
// {64 raster, 22 anti-diagonal}, regs {pins, no-pins, AGPR}: every
// structural alternative regressed. Floor = rendezvous + readlane-hazard +
// dependent-chain latency per serial pixel step (~4700cy at 125us).
// Roles per net: S (spine), Ha: pre {W2NW,W2N} / post {W1NW};
//  Hb: pre {W2NE} / post {W1N,W1NE};  Hc: pre {W2W} / post {W1W}.
// W1 partials parity-double-buffered; W2 partials single-buffered.
// LDS pad cols 0/9 never written -> zero taps at borders for free.

#define NT 512

__device__ __forceinline__ float elu(float x) { return x > 0.f ? x : expm1f(x); }

__device__ __forceinline__ float rdlane(float v, int l) {
  return __int_as_float(__builtin_amdgcn_readlane(__float_as_int(v), l));
}

#define BAR() asm volatile("s_waitcnt lgkmcnt(0)\n\ts_barrier" ::: "memory")

// one 64-dot quarter-step: acc{0..3} += W_[4q+m] * (lane-q broadcast of F_ members)
#define DOT16(W_, F_)                                                \
  _Pragma("unroll")                                                  \
  for (int q = 0; q < 16; ++q) {                                     \
    a0 += (W_)[4*q+0] * rdlane((F_).x, q);                           \
    a1 += (W_)[4*q+1] * rdlane((F_).y, q);                           \
    a2 += (W_)[4*q+2] * rdlane((F_).z, q);                           \
    a3 += (W_)[4*q+3] * rdlane((F_).w, q);                           \
  }

#define FRAG(P_) (reinterpret_cast<const float4*>(P_)[ch & 15])

__global__ __launch_bounds__(NT)
__attribute__((amdgpu_waves_per_eu(2, 2)))
void made_ar_decode_k(
    const float* __restrict__ x,
    const float* __restrict__ mw0, const float* __restrict__ mb0,
    const float* __restrict__ mw1, const float* __restrict__ mb1,
    const float* __restrict__ mw2, const float* __restrict__ mb2,
    const float* __restrict__ mwo, const float* __restrict__ mbo,
    const float* __restrict__ lw0, const float* __restrict__ lb0,
    const float* __restrict__ lw1, const float* __restrict__ lb1,
    const float* __restrict__ lw2, const float* __restrict__ lb2,
    const float* __restrict__ lwo, const float* __restrict__ lbo,
    float* __restrict__ out)
{
  const int b    = blockIdx.x;
  const int tid  = threadIdx.x;
  const int wv   = tid >> 6;       // 0..7
  const int net  = wv & 1;         // 0 = mu, 1 = lv
  const int role = wv >> 1;        // 0:S  1:Hb  2:Ha  3:Hc
  const int ch   = tid & 63;       // lane == out channel

  // parity double-buffered row caches; pcol = spatial col + 1; pad cols 0,9
  // never written -> permanent zeros ('SAME' border).
  __shared__ __align__(16) float h0row[2][2][10][64]; // [net][par][pcol][ch]
  __shared__ __align__(16) float h1row[2][2][10][64];
  __shared__ __align__(16) float yb[2][9][10][4];     // [net][prow][pcol][c]
  __shared__ __align__(16) float xchg[2][2][4];       // [p&1][net][c]
  __shared__ float r1a[2][2][64], r1b[2][2][64], r1c[2][2][64]; // [pix&1][net][ch] W1 partials
  __shared__ float r2a[2][64], r2b[2][64], r2c[2][64];          // [net][ch] W2 partials
  __shared__ float xls[256];

  for (int k = tid; k < 2*2*10*64; k += NT) {
    (&h0row[0][0][0][0])[k] = 0.f;
    (&h1row[0][0][0][0])[k] = 0.f;
  }
  for (int k = tid; k < 2*9*10*4; k += NT) (&yb[0][0][0][0])[k] = 0.f;
  for (int k = tid; k < 2*2*64; k += NT) {
    (&r1a[0][0][0])[k] = 0.f;
    (&r1b[0][0][0])[k] = 0.f;
    (&r1c[0][0][0])[k] = 0.f;
  }
  if (tid < 256) xls[tid] = x[b*256 + tid];   // [c][i][j] flat = c*64 + p

  __syncthreads();   // uniform join after init

  if (role == 0) {
    // ================= S: serial spine =================
    __builtin_amdgcn_s_setprio(1);   // critical-path wave; helpers have slack
    const float* w0g = net ? lw0 : mw0;
    const float* w1g = net ? lw1 : mw1;
    const float* w2g = net ? lw2 : mw2;
    const float* wog = net ? lwo : mwo;
    const int KH[3] = {0,0,0};
    const int KW[3] = {0,1,2};
    float waux[16], wc1[64], wc2[64], wo4[4];
#pragma unroll
    for (int t = 0; t < 3; ++t)
#pragma unroll
      for (int ic = 0; ic < 4; ++ic)
        waux[t*4 + ic] = w0g[((ch*4 + ic)*3 + KH[t])*3 + KW[t]];
#pragma unroll
    for (int ic = 0; ic < 4; ++ic)
      waux[12 + ic] = w0g[((ch*4 + ic)*3 + 1)*3 + 0];   // W tap (1,0)
#pragma unroll
    for (int q = 0; q < 64; ++q) wc1[q] = w1g[((ch*64 + q)*3 + 1)*3 + 1];
#pragma unroll
    for (int q = 0; q < 64; ++q) wc2[q] = w2g[((ch*64 + q)*3 + 1)*3 + 1];
#pragma unroll
    for (int c = 0; c < 4; ++c) wo4[c] = wog[c*64 + ch];
    const float bA = (net ? lb0 : mb0)[ch];
    const float bB = (net ? lb1 : mb1)[ch];
    const float bC = (net ? lb2 : mb2)[ch];
    float boM[4], boL[4];
#pragma unroll
    for (int c = 0; c < 4; ++c) { boM[c] = mbo[c]; boL[c] = lbo[c]; }
    const float boLown = lbo[ch & 3];   // per-lane own-channel ls bias (lanes 0-3 use it)

    float lsacc = 0.f;   // per-lane partial (lanes 0-3 of net 1)
    float y0 = 0.f, y1 = 0.f, y2 = 0.f, y3 = 0.f;   // y(p-1), all lanes

#pragma unroll 1
    for (int p = 0; p < 64; ++p) {
      const int i = p >> 3, j = p & 7, cur = i & 1, pb = p & 1;

      // ---- pre-B1: N-tap reads (old rows, independent) -> epi(p-1) -> h0 -> c1
      float acc = bA;
      {
        const float4 yNW = *reinterpret_cast<const float4*>(&yb[net][i][j    ][0]);
        const float4 yN  = *reinterpret_cast<const float4*>(&yb[net][i][j + 1][0]);
        const float4 yNE = *reinterpret_cast<const float4*>(&yb[net][i][j + 2][0]);
        acc += waux[0]*yNW.x + waux[1]*yNW.y + waux[2]*yNW.z + waux[3]*yNW.w;
        acc += waux[4]*yN.x  + waux[5]*yN.y  + waux[6]*yN.z  + waux[7]*yN.w;
        acc += waux[8]*yNE.x + waux[9]*yNE.y + waux[10]*yNE.z + waux[11]*yNE.w;
      }
      if (p > 0) {
        const int pp = p - 1;
        const float4 m4 = *reinterpret_cast<const float4*>(&xchg[pp & 1][0][0]);
        const float4 l4 = *reinterpret_cast<const float4*>(&xchg[pp & 1][1][0]);
        // y = (x-mu)*exp(-ls): the 1e-12 guard only matters for ls < -20
        // (actual ls is O(1)); saves 4 serialized fp32 div sequences/px.
        y0 = (xls[0*64+pp] - (m4.x + boM[0])) * __expf(-0.5f*(l4.x + boL[0]));
        y1 = (xls[1*64+pp] - (m4.y + boM[1])) * __expf(-0.5f*(l4.y + boL[1]));
        y2 = (xls[2*64+pp] - (m4.z + boM[2])) * __expf(-0.5f*(l4.z + boL[2]));
        y3 = (xls[3*64+pp] - (m4.w + boM[3])) * __expf(-0.5f*(l4.w + boL[3]));
        if (ch == 0)
          *reinterpret_cast<float4*>(&yb[net][(pp>>3)+1][(pp&7)+1][0]) =
              make_float4(y0, y1, y2, y3);
      }
      // W-tap from registers (same floats lane 0 wrote; j==0 -> pad zero)
      if (j > 0) acc += waux[12]*y0 + waux[13]*y1 + waux[14]*y2 + waux[15]*y3;
      const float h0v = elu(acc);
      h0row[net][cur][j + 1][ch] = h0v;

      float c1;
      {
        float a0 = 0.f, a1 = 0.f, a2 = 0.f, a3 = 0.f;
#pragma unroll
        for (int q = 0; q < 16; ++q) {
          a0 += wc1[4*q+0] * rdlane(h0v, 4*q+0);
          a1 += wc1[4*q+1] * rdlane(h0v, 4*q+1);
          a2 += wc1[4*q+2] * rdlane(h0v, 4*q+2);
          a3 += wc1[4*q+3] * rdlane(h0v, 4*q+3);
        }
        c1 = (a0 + a1) + (a2 + a3);
      }

      BAR();   // B1: h0(p), c-partials visible

      // ---- post-B1: h1, c2, h2, out-conv ----
      const float h1v = elu(((c1 + bB) + (r1a[pb][net][ch] + r1b[pb][net][ch]))
                            + r1c[pb][net][ch]);
      h1row[net][cur][j + 1][ch] = h1v;

      float c2;
      {
        float a0 = 0.f, a1 = 0.f, a2 = 0.f, a3 = 0.f;
#pragma unroll
        for (int q = 0; q < 16; ++q) {
          a0 += wc2[4*q+0] * rdlane(h1v, 4*q+0);
          a1 += wc2[4*q+1] * rdlane(h1v, 4*q+1);
          a2 += wc2[4*q+2] * rdlane(h1v, 4*q+2);
          a3 += wc2[4*q+3] * rdlane(h1v, 4*q+3);
        }
        c2 = (a0 + a1) + (a2 + a3);
      }
      const float h2v = elu(((c2 + bC) + (r2a[net][ch] + r2b[net][ch]))
                            + r2c[net][ch]);

      // ---- compact 4-channel reduction: lane l ends with channel l&3 ----
      {
        const float p0 = wo4[0]*h2v, p1 = wo4[1]*h2v;
        const float p2 = wo4[2]*h2v, p3 = wo4[3]*h2v;
        const bool b1 = (ch & 1) != 0, b2 = (ch & 2) != 0;
        float uA = b1 ? p1 : p0, uB = b1 ? p0 : p1;   // channels 0/1
        float vA = b1 ? p3 : p2, vB = b1 ? p2 : p3;   // channels 2/3
        uA += __shfl_xor(uB, 1, 64);   // pair-sum of channel (lane&1)
        vA += __shfl_xor(vB, 1, 64);   // pair-sum of channel 2+(lane&1)
        float s = b2 ? vA : uA;
        float t = b2 ? uA : vA;
        s += __shfl_xor(t, 2, 64);     // 4-lane-group sum of channel lane&3
        s += __shfl_xor(s, 4, 64);
        s += __shfl_xor(s, 8, 64);
        s += __shfl_xor(s, 16, 64);
        s += __shfl_xor(s, 32, 64);    // full sum of channel lane&3
        if (ch < 4) {
          xchg[p & 1][net][ch] = s;    // lanes 0-3 hold channels 0-3
          if (net == 1) lsacc += 0.5f*(s + boLown);
        }
      }

      BAR();   // B2
    }

    // final y(63) into yb (for the copy-out)
    {
      const float4 m4 = *reinterpret_cast<const float4*>(&xchg[1][0][0]);
      const float4 l4 = *reinterpret_cast<const float4*>(&xchg[1][1][0]);
      float fy0 = (xls[0*64+63] - (m4.x + boM[0])) * __expf(-0.5f*(l4.x + boL[0]));
      float fy1 = (xls[1*64+63] - (m4.y + boM[1])) * __expf(-0.5f*(l4.y + boL[1]));
      float fy2 = (xls[2*64+63] - (m4.z + boM[2])) * __expf(-0.5f*(l4.z + boL[2]));
      float fy3 = (xls[3*64+63] - (m4.w + boM[3])) * __expf(-0.5f*(l4.w + boL[3]));
      if (ch == 0)
        *reinterpret_cast<float4*>(&yb[net][8][8][0]) = make_float4(fy0, fy1, fy2, fy3);
    }
    if (net == 1) {
      float t = lsacc;                 // lanes 0-3 hold per-channel partials
      t += __shfl_xor(t, 1, 64);
      t += __shfl_xor(t, 2, 64);
      if (ch == 0) out[32*4*64 + b] = t;
    }
    __builtin_amdgcn_s_setprio(0);

  } else if (role == 1) {
    // ===== Hb: pre {W2 NE} ; post {W1 N, W1 NE (for p+1)} =====
    const float* w1g = net ? lw1 : mw1;
    const float* w2g = net ? lw2 : mw2;
    float w2ne[64], w1n[64], w1ne[64];
#pragma unroll
    for (int q = 0; q < 64; ++q) {
      w2ne[q] = w2g[((ch*64 + q)*3 + 0)*3 + 2];
      w1n [q] = w1g[((ch*64 + q)*3 + 0)*3 + 1];
      w1ne[q] = w1g[((ch*64 + q)*3 + 0)*3 + 2];
    }
#pragma unroll 1
    for (int p = 0; p < 64; ++p) {
      const int i = p >> 3, j = p & 7, cur = i & 1, prv = cur ^ 1;
      {
        const float4 f = FRAG(&h1row[net][prv][j + 2][0]);
        float a0 = 0.f, a1 = 0.f, a2 = 0.f, a3 = 0.f;
        DOT16(w2ne, f);
        r2b[net][ch] = (a0 + a1) + (a2 + a3);
      }
      BAR();
      if (p < 63) {
        const int p2 = p + 1, i2 = p2 >> 3, j2 = p2 & 7;
        float v = 0.f;
        if (i2 >= 1) {
          const int sp = (i2 - 1) & 1;
          const float4 fN  = FRAG(&h0row[net][sp][j2 + 1][0]);
          const float4 fNE = FRAG(&h0row[net][sp][j2 + 2][0]);
          float a0 = 0.f, a1 = 0.f, a2 = 0.f, a3 = 0.f;
          DOT16(w1n,  fN);
          DOT16(w1ne, fNE);
          v = (a0 + a1) + (a2 + a3);
        }
        r1b[p2 & 1][net][ch] = v;
      }
      BAR();
    }

  } else if (role == 2) {
    // ===== Ha: pre {W2 NW, W2 N} ; post {W1 NW (for p+1)} =====
    const float* w1g = net ? lw1 : mw1;
    const float* w2g = net ? lw2 : mw2;
    float w2nw[64], w2n[64], w1nw[64];
#pragma unroll
    for (int q = 0; q < 64; ++q) {
      w2nw[q] = w2g[((ch*64 + q)*3 + 0)*3 + 0];
      w2n [q] = w2g[((ch*64 + q)*3 + 0)*3 + 1];
      w1nw[q] = w1g[((ch*64 + q)*3 + 0)*3 + 0];
    }
#pragma unroll 1
    for (int p = 0; p < 64; ++p) {
      const int i = p >> 3, j = p & 7, cur = i & 1, prv = cur ^ 1;
      {
        const float4 fNW = FRAG(&h1row[net][prv][j    ][0]);
        const float4 fN  = FRAG(&h1row[net][prv][j + 1][0]);
        float a0 = 0.f, a1 = 0.f, a2 = 0.f, a3 = 0.f;
        DOT16(w2nw, fNW);
        DOT16(w2n,  fN);
        r2a[net][ch] = (a0 + a1) + (a2 + a3);
      }
      BAR();
      if (p < 63) {
        const int p2 = p + 1, i2 = p2 >> 3, j2 = p2 & 7;
        float v = 0.f;
        if (i2 >= 1) {
          const int sp = (i2 - 1) & 1;
          const float4 f = FRAG(&h0row[net][sp][j2][0]);
          float a0 = 0.f, a1 = 0.f, a2 = 0.f, a3 = 0.f;
          DOT16(w1nw, f);
          v = (a0 + a1) + (a2 + a3);
        }
        r1a[p2 & 1][net][ch] = v;
      }
      BAR();
    }

  } else {
    // ===== Hc: pre {W2 W vs h1(p-1)} ; post {W1 W vs h0(p) (for p+1)} =====
    const float* w1g = net ? lw1 : mw1;
    const float* w2g = net ? lw2 : mw2;
    float w2w[64], w1w[64];
#pragma unroll
    for (int q = 0; q < 64; ++q) {
      w2w[q] = w2g[((ch*64 + q)*3 + 1)*3 + 0];
      w1w[q] = w1g[((ch*64 + q)*3 + 1)*3 + 0];
    }
#pragma unroll 1
    for (int p = 0; p < 64; ++p) {
      const int i = p >> 3, j = p & 7, cur = i & 1;
      {
        // pcol j: pad col 0 gives zero at j==0 automatically
        const float4 f = FRAG(&h1row[net][cur][j][0]);
        float a0 = 0.f, a1 = 0.f, a2 = 0.f, a3 = 0.f;
        DOT16(w2w, f);
        r2c[net][ch] = (a0 + a1) + (a2 + a3);
      }
      BAR();
      if (p < 63) {
        const int p2 = p + 1, j2 = p2 & 7;
        float v = 0.f;
        if (j2 > 0) {   // same row: W tap = h0(p), just written pre-B1
          const float4 f = FRAG(&h0row[net][cur][j + 1][0]);
          float a0 = 0.f, a1 = 0.f, a2 = 0.f, a3 = 0.f;
          DOT16(w1w, f);
          v = (a0 + a1) + (a2 + a3);
        }
        r1c[p2 & 1][net][ch] = v;
      }
      BAR();
    }
  }

  BAR();   // join: yb complete (incl. y(63))

  // copy-out: y from net-0's yb
  if (tid < 256) {
    const int c = tid >> 6, p = tid & 63;
    out[(b*4 + c)*64 + p] = yb[0][(p >> 3) + 1][(p & 7) + 1][c];
  }
}

extern "C" void kernel_launch(void* const* d_in, const int* in_sizes, int n_in,
                              void* d_out, int out_size, void* d_ws, size_t ws_size,
                              hipStream_t stream) {
  (void)in_sizes; (void)n_in; (void)out_size; (void)d_ws; (void)ws_size;
  made_ar_decode_k<<<dim3(32), dim3(NT), 0, stream>>>(
      (const float*)d_in[0],
      (const float*)d_in[1],  (const float*)d_in[2],
      (const float*)d_in[3],  (const float*)d_in[4],
      (const float*)d_in[5],  (const float*)d_in[6],
      (const float*)d_in[7],  (const float*)d_in[8],
      (const float*)d_in[9],  (const float*)d_in[10],
      (const float*)d_in[11], (const float*)d_in[12],
      (const float*)d_in[13], (const float*)d_in[14],
      (const float*)d_in[15], (const float*)d_in[16],
      (float*)d_out);
}

// Round 23
// 205.583 us; speedup vs baseline: 1.0183x; 1.0183x over previous
//
#include <hip/hip_runtime.h>

// MADE / PixelCNN autoregressive inverse (all fp32, per reference).
//
// FINAL KERNEL (r21; session best: 125.2us rocprof / 207.4us harness).
// r22's W-tap-from-reg reorder was neutral (+2us) -> reverted.
//
// 23-round ledger: 7 structural rewrites (deep-chain, anti-diagonal
// wavefront, spin-flags x3, 12-wave flatten, spine-owns-all) ALL regressed;
// 2 on-chain shaves won ~1:1 (r19 divide removal -5.7us, r21 compact
// butterfly -5.8us); MAC style irrelevant on spine, DOTU in helpers
// regresses (single LDS pipe vs 4 VALU SIMDs). The kernel sits at a
// LATENCY FLOOR (0.26% HBM, 5.6% VALU, no spill): ~4700cy/pixel =
// 2x 8-wave barrier rendezvous + spine issue + readlane hazards +
// dependent-chain hops at the throttled clock of a 32-CU dispatch.
// 1-barrier variants recreate either the >256-VGPR spill wall (r17) or
// the helper race topology (r15) -- both measured failures.
//
// Structure (r11 2-barrier/8-wave balanced schedule):
//  * W1 off-center taps for p+1 need only h0(<=p) -> helpers' POST-B1
//    phase (overlaps spine h1->c2->h2->butterfly); pre-B1 keeps W2 dots.
//  * W1 partials parity-double-buffered; W2 partials single-buffered.
//  * r19: epilogue y = (x-mu)*__expf(-ls) (no fp32 div on chain; eps
//    guard only matters for ls < -20, actual ls is O(1)).
//  * r21: compact out-conv reduction (6 shfl vs 24; lane l owns ch l&3).
// Roles per net: S (spine), Ha: pre {W2NW,W2N} / post {W1NW};
//  Hb: pre {W2NE} / post {W1N,W1NE};  Hc: pre {W2W} / post {W1W}.
// LDS pad cols 0/9 never written -> zero taps at borders for free.

#define NT 512

__device__ __forceinline__ float elu(float x) { return x > 0.f ? x : expm1f(x); }

__device__ __forceinline__ float rdlane(float v, int l) {
  return __int_as_float(__builtin_amdgcn_readlane(__float_as_int(v), l));
}

#define BAR() asm volatile("s_waitcnt lgkmcnt(0)\n\ts_barrier" ::: "memory")

// one 64-dot quarter-step: acc{0..3} += W_[4q+m] * (lane-q broadcast of F_ members)
#define DOT16(W_, F_)                                                \
  _Pragma("unroll")                                                  \
  for (int q = 0; q < 16; ++q) {                                     \
    a0 += (W_)[4*q+0] * rdlane((F_).x, q);                           \
    a1 += (W_)[4*q+1] * rdlane((F_).y, q);                           \
    a2 += (W_)[4*q+2] * rdlane((F_).z, q);                           \
    a3 += (W_)[4*q+3] * rdlane((F_).w, q);                           \
  }

#define FRAG(P_) (reinterpret_cast<const float4*>(P_)[ch & 15])

__global__ __launch_bounds__(NT)
__attribute__((amdgpu_waves_per_eu(2, 2)))
void made_ar_decode_k(
    const float* __restrict__ x,
    const float* __restrict__ mw0, const float* __restrict__ mb0,
    const float* __restrict__ mw1, const float* __restrict__ mb1,
    const float* __restrict__ mw2, const float* __restrict__ mb2,
    const float* __restrict__ mwo, const float* __restrict__ mbo,
    const float* __restrict__ lw0, const float* __restrict__ lb0,
    const float* __restrict__ lw1, const float* __restrict__ lb1,
    const float* __restrict__ lw2, const float* __restrict__ lb2,
    const float* __restrict__ lwo, const float* __restrict__ lbo,
    float* __restrict__ out)
{
  const int b    = blockIdx.x;
  const int tid  = threadIdx.x;
  const int wv   = tid >> 6;       // 0..7
  const int net  = wv & 1;         // 0 = mu, 1 = lv
  const int role = wv >> 1;        // 0:S  1:Hb  2:Ha  3:Hc
  const int ch   = tid & 63;       // lane == out channel

  // parity double-buffered row caches; pcol = spatial col + 1; pad cols 0,9
  // never written -> permanent zeros ('SAME' border).
  __shared__ __align__(16) float h0row[2][2][10][64]; // [net][par][pcol][ch]
  __shared__ __align__(16) float h1row[2][2][10][64];
  __shared__ __align__(16) float yb[2][9][10][4];     // [net][prow][pcol][c]
  __shared__ __align__(16) float xchg[2][2][4];       // [p&1][net][c]
  __shared__ float r1a[2][2][64], r1b[2][2][64], r1c[2][2][64]; // [pix&1][net][ch] W1 partials
  __shared__ float r2a[2][64], r2b[2][64], r2c[2][64];          // [net][ch] W2 partials
  __shared__ float xls[256];

  for (int k = tid; k < 2*2*10*64; k += NT) {
    (&h0row[0][0][0][0])[k] = 0.f;
    (&h1row[0][0][0][0])[k] = 0.f;
  }
  for (int k = tid; k < 2*9*10*4; k += NT) (&yb[0][0][0][0])[k] = 0.f;
  for (int k = tid; k < 2*2*64; k += NT) {
    (&r1a[0][0][0])[k] = 0.f;
    (&r1b[0][0][0])[k] = 0.f;
    (&r1c[0][0][0])[k] = 0.f;
  }
  if (tid < 256) xls[tid] = x[b*256 + tid];   // [c][i][j] flat = c*64 + p

  __syncthreads();   // uniform join after init

  if (role == 0) {
    // ================= S: serial spine =================
    __builtin_amdgcn_s_setprio(1);   // critical-path wave; helpers have slack
    const float* w0g = net ? lw0 : mw0;
    const float* w1g = net ? lw1 : mw1;
    const float* w2g = net ? lw2 : mw2;
    const float* wog = net ? lwo : mwo;
    const int KH[4] = {0,0,0,1};
    const int KW[4] = {0,1,2,0};
    float waux[16], wc1[64], wc2[64], wo4[4];
#pragma unroll
    for (int t = 0; t < 4; ++t)
#pragma unroll
      for (int ic = 0; ic < 4; ++ic)
        waux[t*4 + ic] = w0g[((ch*4 + ic)*3 + KH[t])*3 + KW[t]];
#pragma unroll
    for (int q = 0; q < 64; ++q) wc1[q] = w1g[((ch*64 + q)*3 + 1)*3 + 1];
#pragma unroll
    for (int q = 0; q < 64; ++q) wc2[q] = w2g[((ch*64 + q)*3 + 1)*3 + 1];
#pragma unroll
    for (int c = 0; c < 4; ++c) wo4[c] = wog[c*64 + ch];
    const float bA = (net ? lb0 : mb0)[ch];
    const float bB = (net ? lb1 : mb1)[ch];
    const float bC = (net ? lb2 : mb2)[ch];
    float boM[4], boL[4];
#pragma unroll
    for (int c = 0; c < 4; ++c) { boM[c] = mbo[c]; boL[c] = lbo[c]; }
    const float boLown = lbo[ch & 3];   // per-lane own-channel ls bias (lanes 0-3 use it)

    float lsacc = 0.f;   // per-lane partial (lanes 0-3 of net 1)

#pragma unroll 1
    for (int p = 0; p < 64; ++p) {
      const int i = p >> 3, j = p & 7, cur = i & 1, pb = p & 1;

      // ---- pre-B1: epi(p-1), h0(p), c1 ----
      if (p > 0) {
        const int pp = p - 1;
        const float4 m4 = *reinterpret_cast<const float4*>(&xchg[pp & 1][0][0]);
        const float4 l4 = *reinterpret_cast<const float4*>(&xchg[pp & 1][1][0]);
        // y = (x-mu)*exp(-ls): the 1e-12 guard only matters for ls < -20
        // (actual ls is O(1)); saves 4 serialized fp32 div sequences/px.
        float y0 = (xls[0*64+pp] - (m4.x + boM[0])) * __expf(-0.5f*(l4.x + boL[0]));
        float y1 = (xls[1*64+pp] - (m4.y + boM[1])) * __expf(-0.5f*(l4.y + boL[1]));
        float y2 = (xls[2*64+pp] - (m4.z + boM[2])) * __expf(-0.5f*(l4.z + boL[2]));
        float y3 = (xls[3*64+pp] - (m4.w + boM[3])) * __expf(-0.5f*(l4.w + boL[3]));
        if (ch == 0)
          *reinterpret_cast<float4*>(&yb[net][(pp>>3)+1][(pp&7)+1][0]) =
              make_float4(y0, y1, y2, y3);
      }
      float acc = bA;
#pragma unroll
      for (int t = 0; t < 4; ++t) {
        const float4 yv = *reinterpret_cast<const float4*>(&yb[net][i + KH[t]][j + KW[t]][0]);
        acc += waux[t*4+0]*yv.x + waux[t*4+1]*yv.y
             + waux[t*4+2]*yv.z + waux[t*4+3]*yv.w;
      }
      const float h0v = elu(acc);
      h0row[net][cur][j + 1][ch] = h0v;

      float c1;
      {
        float a0 = 0.f, a1 = 0.f, a2 = 0.f, a3 = 0.f;
#pragma unroll
        for (int q = 0; q < 16; ++q) {
          a0 += wc1[4*q+0] * rdlane(h0v, 4*q+0);
          a1 += wc1[4*q+1] * rdlane(h0v, 4*q+1);
          a2 += wc1[4*q+2] * rdlane(h0v, 4*q+2);
          a3 += wc1[4*q+3] * rdlane(h0v, 4*q+3);
        }
        c1 = (a0 + a1) + (a2 + a3);
      }

      BAR();   // B1: h0(p), c-partials visible

      // ---- post-B1: h1, c2, h2, out-conv ----
      const float h1v = elu(((c1 + bB) + (r1a[pb][net][ch] + r1b[pb][net][ch]))
                            + r1c[pb][net][ch]);
      h1row[net][cur][j + 1][ch] = h1v;

      float c2;
      {
        float a0 = 0.f, a1 = 0.f, a2 = 0.f, a3 = 0.f;
#pragma unroll
        for (int q = 0; q < 16; ++q) {
          a0 += wc2[4*q+0] * rdlane(h1v, 4*q+0);
          a1 += wc2[4*q+1] * rdlane(h1v, 4*q+1);
          a2 += wc2[4*q+2] * rdlane(h1v, 4*q+2);
          a3 += wc2[4*q+3] * rdlane(h1v, 4*q+3);
        }
        c2 = (a0 + a1) + (a2 + a3);
      }
      const float h2v = elu(((c2 + bC) + (r2a[net][ch] + r2b[net][ch]))
                            + r2c[net][ch]);

      // ---- compact 4-channel reduction: lane l ends with channel l&3 ----
      {
        const float p0 = wo4[0]*h2v, p1 = wo4[1]*h2v;
        const float p2 = wo4[2]*h2v, p3 = wo4[3]*h2v;
        const bool b1 = (ch & 1) != 0, b2 = (ch & 2) != 0;
        float uA = b1 ? p1 : p0, uB = b1 ? p0 : p1;   // channels 0/1
        float vA = b1 ? p3 : p2, vB = b1 ? p2 : p3;   // channels 2/3
        uA += __shfl_xor(uB, 1, 64);   // pair-sum of channel (lane&1)
        vA += __shfl_xor(vB, 1, 64);   // pair-sum of channel 2+(lane&1)
        float s = b2 ? vA : uA;
        float t = b2 ? uA : vA;
        s += __shfl_xor(t, 2, 64);     // 4-lane-group sum of channel lane&3
        s += __shfl_xor(s, 4, 64);
        s += __shfl_xor(s, 8, 64);
        s += __shfl_xor(s, 16, 64);
        s += __shfl_xor(s, 32, 64);    // full sum of channel lane&3
        if (ch < 4) {
          xchg[p & 1][net][ch] = s;    // lanes 0-3 hold channels 0-3
          if (net == 1) lsacc += 0.5f*(s + boLown);
        }
      }

      BAR();   // B2
    }

    // final y(63) into yb (for the copy-out)
    {
      const float4 m4 = *reinterpret_cast<const float4*>(&xchg[1][0][0]);
      const float4 l4 = *reinterpret_cast<const float4*>(&xchg[1][1][0]);
      float y0 = (xls[0*64+63] - (m4.x + boM[0])) * __expf(-0.5f*(l4.x + boL[0]));
      float y1 = (xls[1*64+63] - (m4.y + boM[1])) * __expf(-0.5f*(l4.y + boL[1]));
      float y2 = (xls[2*64+63] - (m4.z + boM[2])) * __expf(-0.5f*(l4.z + boL[2]));
      float y3 = (xls[3*64+63] - (m4.w + boM[3])) * __expf(-0.5f*(l4.w + boL[3]));
      if (ch == 0)
        *reinterpret_cast<float4*>(&yb[net][8][8][0]) = make_float4(y0, y1, y2, y3);
    }
    if (net == 1) {
      float t = lsacc;                 // lanes 0-3 hold per-channel partials
      t += __shfl_xor(t, 1, 64);
      t += __shfl_xor(t, 2, 64);
      if (ch == 0) out[32*4*64 + b] = t;
    }
    __builtin_amdgcn_s_setprio(0);

  } else if (role == 1) {
    // ===== Hb: pre {W2 NE} ; post {W1 N, W1 NE (for p+1)} =====
    const float* w1g = net ? lw1 : mw1;
    const float* w2g = net ? lw2 : mw2;
    float w2ne[64], w1n[64], w1ne[64];
#pragma unroll
    for (int q = 0; q < 64; ++q) {
      w2ne[q] = w2g[((ch*64 + q)*3 + 0)*3 + 2];
      w1n [q] = w1g[((ch*64 + q)*3 + 0)*3 + 1];
      w1ne[q] = w1g[((ch*64 + q)*3 + 0)*3 + 2];
    }
#pragma unroll 1
    for (int p = 0; p < 64; ++p) {
      const int i = p >> 3, j = p & 7, cur = i & 1, prv = cur ^ 1;
      {
        const float4 f = FRAG(&h1row[net][prv][j + 2][0]);
        float a0 = 0.f, a1 = 0.f, a2 = 0.f, a3 = 0.f;
        DOT16(w2ne, f);
        r2b[net][ch] = (a0 + a1) + (a2 + a3);
      }
      BAR();
      if (p < 63) {
        const int p2 = p + 1, i2 = p2 >> 3, j2 = p2 & 7;
        float v = 0.f;
        if (i2 >= 1) {
          const int sp = (i2 - 1) & 1;
          const float4 fN  = FRAG(&h0row[net][sp][j2 + 1][0]);
          const float4 fNE = FRAG(&h0row[net][sp][j2 + 2][0]);
          float a0 = 0.f, a1 = 0.f, a2 = 0.f, a3 = 0.f;
          DOT16(w1n,  fN);
          DOT16(w1ne, fNE);
          v = (a0 + a1) + (a2 + a3);
        }
        r1b[p2 & 1][net][ch] = v;
      }
      BAR();
    }

  } else if (role == 2) {
    // ===== Ha: pre {W2 NW, W2 N} ; post {W1 NW (for p+1)} =====
    const float* w1g = net ? lw1 : mw1;
    const float* w2g = net ? lw2 : mw2;
    float w2nw[64], w2n[64], w1nw[64];
#pragma unroll
    for (int q = 0; q < 64; ++q) {
      w2nw[q] = w2g[((ch*64 + q)*3 + 0)*3 + 0];
      w2n [q] = w2g[((ch*64 + q)*3 + 0)*3 + 1];
      w1nw[q] = w1g[((ch*64 + q)*3 + 0)*3 + 0];
    }
#pragma unroll 1
    for (int p = 0; p < 64; ++p) {
      const int i = p >> 3, j = p & 7, cur = i & 1, prv = cur ^ 1;
      {
        const float4 fNW = FRAG(&h1row[net][prv][j    ][0]);
        const float4 fN  = FRAG(&h1row[net][prv][j + 1][0]);
        float a0 = 0.f, a1 = 0.f, a2 = 0.f, a3 = 0.f;
        DOT16(w2nw, fNW);
        DOT16(w2n,  fN);
        r2a[net][ch] = (a0 + a1) + (a2 + a3);
      }
      BAR();
      if (p < 63) {
        const int p2 = p + 1, i2 = p2 >> 3, j2 = p2 & 7;
        float v = 0.f;
        if (i2 >= 1) {
          const int sp = (i2 - 1) & 1;
          const float4 f = FRAG(&h0row[net][sp][j2][0]);
          float a0 = 0.f, a1 = 0.f, a2 = 0.f, a3 = 0.f;
          DOT16(w1nw, f);
          v = (a0 + a1) + (a2 + a3);
        }
        r1a[p2 & 1][net][ch] = v;
      }
      BAR();
    }

  } else {
    // ===== Hc: pre {W2 W vs h1(p-1)} ; post {W1 W vs h0(p) (for p+1)} =====
    const float* w1g = net ? lw1 : mw1;
    const float* w2g = net ? lw2 : mw2;
    float w2w[64], w1w[64];
#pragma unroll
    for (int q = 0; q < 64; ++q) {
      w2w[q] = w2g[((ch*64 + q)*3 + 1)*3 + 0];
      w1w[q] = w1g[((ch*64 + q)*3 + 1)*3 + 0];
    }
#pragma unroll 1
    for (int p = 0; p < 64; ++p) {
      const int i = p >> 3, j = p & 7, cur = i & 1;
      {
        // pcol j: pad col 0 gives zero at j==0 automatically
        const float4 f = FRAG(&h1row[net][cur][j][0]);
        float a0 = 0.f, a1 = 0.f, a2 = 0.f, a3 = 0.f;
        DOT16(w2w, f);
        r2c[net][ch] = (a0 + a1) + (a2 + a3);
      }
      BAR();
      if (p < 63) {
        const int p2 = p + 1, j2 = p2 & 7;
        float v = 0.f;
        if (j2 > 0) {   // same row: W tap = h0(p), just written pre-B1
          const float4 f = FRAG(&h0row[net][cur][j + 1][0]);
          float a0 = 0.f, a1 = 0.f, a2 = 0.f, a3 = 0.f;
          DOT16(w1w, f);
          v = (a0 + a1) + (a2 + a3);
        }
        r1c[p2 & 1][net][ch] = v;
      }
      BAR();
    }
  }

  BAR();   // join: yb complete (incl. y(63))

  // copy-out: y from net-0's yb
  if (tid < 256) {
    const int c = tid >> 6, p = tid & 63;
    out[(b*4 + c)*64 + p] = yb[0][(p >> 3) + 1][(p & 7) + 1][c];
  }
}

extern "C" void kernel_launch(void* const* d_in, const int* in_sizes, int n_in,
                              void* d_out, int out_size, void* d_ws, size_t ws_size,
                              hipStream_t stream) {
  (void)in_sizes; (void)n_in; (void)out_size; (void)d_ws; (void)ws_size;
  made_ar_decode_k<<<dim3(32), dim3(NT), 0, stream>>>(
      (const float*)d_in[0],
      (const float*)d_in[1],  (const float*)d_in[2],
      (const float*)d_in[3],  (const float*)d_in[4],
      (const float*)d_in[5],  (const float*)d_in[6],
      (const float*)d_in[7],  (const float*)d_in[8],
      (const float*)d_in[9],  (const float*)d_in[10],
      (const float*)d_in[11], (const float*)d_in[12],
      (const float*)d_in[13], (const float*)d_in[14],
      (const float*)d_in[15], (const float*)d_in[16],
      (float*)d_out);
}